// Round 11
// baseline (1201.027 us; speedup 1.0000x reference)
//
#include <hip/hip_runtime.h>
#include <hip/hip_bf16.h>

// MoE MLP: B=4, L=2048, D=1024, E=8, H=4096, top-2. T=8192 tokens, 16384 assignments.
// Round 11: r10 structure (dbuf [row][40] f16 LDS, b128 frags, verified) +
// (1) uniform-base int-offset addressing (saddr form) for all K-loop global loads,
// (2) 2-deep register prefetch, 2 static reg sets, 2 barriers per 2 K-steps.
// Router/combine/epilogues byte-identical to r10 (verified).

#define TOK  8192
#define DDIM 1024
#define NEXP 8
#define HDIM 4096

typedef __attribute__((ext_vector_type(8))) _Float16 f16x8;
typedef __attribute__((ext_vector_type(4))) float    f32x4;

static constexpr size_t OFF_COUNTS  = 0;
static constexpr size_t OFF_TOKENS  = 4096;
static constexpr size_t OFF_WEIGHTS = OFF_TOKENS + (size_t)NEXP * TOK * 4;
static constexpr size_t OFF_SLOTS   = OFF_WEIGHTS + (size_t)NEXP * TOK * 4;
static constexpr size_t OFF_H       = 1ull << 20;
static constexpr size_t OFF_Y       = OFF_H + (1ull << 27);

// ---------------- Router (verified r1/r5-r10) ----------------
__global__ __launch_bounds__(256) void router_k(
    const float* __restrict__ x, const float* __restrict__ Wr,
    int* __restrict__ counts, int* __restrict__ tokens, float* __restrict__ weights,
    int* __restrict__ slots) {
  const int lane = threadIdx.x & 63;
  const int t = blockIdx.x * 4 + (threadIdx.x >> 6);
  const float* xr = x + (size_t)t * DDIM;

  float acc[NEXP];
#pragma unroll
  for (int e = 0; e < NEXP; ++e) acc[e] = 0.f;

#pragma unroll
  for (int it = 0; it < DDIM / 256; ++it) {
    const int d = it * 256 + lane * 4;
    const float4 xv = *(const float4*)(xr + d);
    const float* wr = Wr + (size_t)d * NEXP;
#pragma unroll
    for (int j = 0; j < 4; ++j) {
      const float xs = (j == 0) ? xv.x : (j == 1) ? xv.y : (j == 2) ? xv.z : xv.w;
      const float4 w0 = *(const float4*)(wr + j * NEXP);
      const float4 w1 = *(const float4*)(wr + j * NEXP + 4);
      acc[0] = fmaf(xs, w0.x, acc[0]); acc[1] = fmaf(xs, w0.y, acc[1]);
      acc[2] = fmaf(xs, w0.z, acc[2]); acc[3] = fmaf(xs, w0.w, acc[3]);
      acc[4] = fmaf(xs, w1.x, acc[4]); acc[5] = fmaf(xs, w1.y, acc[5]);
      acc[6] = fmaf(xs, w1.z, acc[6]); acc[7] = fmaf(xs, w1.w, acc[7]);
    }
  }
#pragma unroll
  for (int e = 0; e < NEXP; ++e) {
#pragma unroll
    for (int off = 32; off > 0; off >>= 1) acc[e] += __shfl_xor(acc[e], off);
  }
  if (lane == 0) {
    int i0 = 0; float v0 = acc[0];
#pragma unroll
    for (int e = 1; e < NEXP; ++e) if (acc[e] > v0) { v0 = acc[e]; i0 = e; }
    int i1 = -1; float v1 = -3.4e38f;
#pragma unroll
    for (int e = 0; e < NEXP; ++e) if (e != i0 && acc[e] > v1) { v1 = acc[e]; i1 = e; }
    const float r = expf(v1 - v0);
    const float inv = 1.f / (1.f + r);
    const int p0 = atomicAdd(counts + i0 * 64, 1);
    tokens[i0 * TOK + p0] = t; weights[i0 * TOK + p0] = inv;
    const int p1 = atomicAdd(counts + i1 * 64, 1);
    tokens[i1 * TOK + p1] = t; weights[i1 * TOK + p1] = r * inv;
    slots[t * 2]     = (i0 << 16) | p0;
    slots[t * 2 + 1] = (i1 << 16) | p1;
  }
}

// LDS tiles [row][40] f16 (80B stride): b128 frag reads ~2-way (free);
// staged writes ~4-way. Verified r5/r6/r10.

// B loads: uniform base + int dword offset (saddr form), 16 loads, imm for 32*g.
template <int LD>
__device__ __forceinline__ void b_loadi(const float* __restrict__ Wb, int o, float (&bv)[4][4]) {
#pragma unroll
  for (int g = 0; g < 4; ++g)
#pragma unroll
    for (int j = 0; j < 4; ++j)
      bv[g][j] = Wb[o + j * LD + 32 * g];
}

__device__ __forceinline__ void b_store(int bn, int bk4, const float (&bv)[4][4],
                                        _Float16 (*Bs)[40]) {
#pragma unroll
  for (int g = 0; g < 4; ++g) {
    const unsigned p0 = __builtin_bit_cast(unsigned, __builtin_amdgcn_cvt_pkrtz(bv[g][0], bv[g][1]));
    const unsigned p1 = __builtin_bit_cast(unsigned, __builtin_amdgcn_cvt_pkrtz(bv[g][2], bv[g][3]));
    *(uint2*)&Bs[bn + 32 * g][bk4] = make_uint2(p0, p1);
  }
}

__device__ __forceinline__ void a_loadi(const float* __restrict__ xb, int o, float4 (&av)[4]) {
#pragma unroll
  for (int j = 0; j < 4; ++j) av[j] = *(const float4*)(xb + o + j * 4);
}

__device__ __forceinline__ void a1_store(const float4 (&av)[4], int ar, int aseg,
                                         _Float16 (*As)[40]) {
  unsigned u[8];
#pragma unroll
  for (int j = 0; j < 4; ++j) {
    u[j * 2]     = __builtin_bit_cast(unsigned, __builtin_amdgcn_cvt_pkrtz(av[j].x, av[j].y));
    u[j * 2 + 1] = __builtin_bit_cast(unsigned, __builtin_amdgcn_cvt_pkrtz(av[j].z, av[j].w));
  }
  *(uint4*)&As[ar][aseg]     = make_uint4(u[0], u[1], u[2], u[3]);
  *(uint4*)&As[ar][aseg + 8] = make_uint4(u[4], u[5], u[6], u[7]);
}

__device__ __forceinline__ void a2_loadi(const _Float16* __restrict__ hb, int o, uint4 (&av)[2]) {
  av[0] = *(const uint4*)(hb + o);
  av[1] = *(const uint4*)(hb + o + 8);
}

// Fragment read + 16 MFMA (layouts HW-verified r5-r10).
__device__ __forceinline__ void g_compute(const _Float16 (*As)[40], const _Float16 (*Bs)[40],
                                          int wr, int wc, int lane, f32x4 (&acc)[4][4]) {
  const int l15 = lane & 15, g8 = (lane >> 4) * 8;
  f16x8 af[4], bf[4];
#pragma unroll
  for (int mf = 0; mf < 4; ++mf) af[mf] = *(const f16x8*)&As[wr + mf * 16 + l15][g8];
#pragma unroll
  for (int nf = 0; nf < 4; ++nf) bf[nf] = *(const f16x8*)&Bs[wc + nf * 16 + l15][g8];
#pragma unroll
  for (int mf = 0; mf < 4; ++mf)
#pragma unroll
    for (int nf = 0; nf < 4; ++nf)
      acc[mf][nf] = __builtin_amdgcn_mfma_f32_16x16x32_f16(af[mf], bf[nf], acc[mf][nf], 0, 0, 0);
}

// ---------------- GEMM1: h = silu(gather(x) @ W1[e]) ----------------
__global__ __launch_bounds__(256) void gemm1_k(
    const float* __restrict__ x, const float* __restrict__ W1,
    const int* __restrict__ counts, const int* __restrict__ tokens,
    _Float16* __restrict__ hbuf) {
  const int e = blockIdx.z;
  const int n_e = counts[e * 64];
  const int m0 = blockIdx.y * 128;
  if (m0 >= n_e) return;
  const int n0 = blockIdx.x * 128;
  int off = 0;
#pragma unroll
  for (int i = 0; i < NEXP; ++i) off += (i < e) ? counts[i * 64] : 0;

  __shared__ __align__(16) _Float16 As[2][128][40];
  __shared__ __align__(16) _Float16 Bs[2][128][40];

  const int tid = threadIdx.x, lane = tid & 63, w = tid >> 6;
  const int wr = (w >> 1) * 64, wc = (w & 1) * 64;

  const int ar = tid >> 1, aseg = (tid & 1) * 16;
  const int rA = m0 + ar;
  const int tokA = (rA < n_e) ? tokens[e * TOK + rA] : 0;
  const int ao = tokA * DDIM + aseg;                 // int dword offset into x
  const int bn = tid & 31, bk4 = (tid >> 5) * 4;
  const float* __restrict__ Wb = W1 + (size_t)e * DDIM * HDIM;   // uniform base
  const int bo = bk4 * HDIM + n0 + bn;               // int dword offset

  f32x4 acc[4][4] = {};

  float4 avs[4], avt[4]; float bvs[4][4], bvt[4][4];
  a_loadi(x, ao, avs);           b_loadi<HDIM>(Wb, bo, bvs);
  a_loadi(x, ao + 32, avt);      b_loadi<HDIM>(Wb, bo + 32 * HDIM, bvt);
  a1_store(avs, ar, aseg, As[0]); b_store(bn, bk4, bvs, Bs[0]);
  __syncthreads();

  constexpr int NS = DDIM / 32;                      // 32 K-steps
  for (int t = 0; t < NS; t += 2) {
    if (t + 2 < NS) { a_loadi(x, ao + (t + 2) * 32, avs); b_loadi<HDIM>(Wb, bo + (t + 2) * 32 * HDIM, bvs); }
    g_compute(As[0], Bs[0], wr, wc, lane, acc);      // step t
    a1_store(avt, ar, aseg, As[1]); b_store(bn, bk4, bvt, Bs[1]);   // publish t+1
    __syncthreads();
    if (t + 3 < NS) { a_loadi(x, ao + (t + 3) * 32, avt); b_loadi<HDIM>(Wb, bo + (t + 3) * 32 * HDIM, bvt); }
    g_compute(As[1], Bs[1], wr, wc, lane, acc);      // step t+1
    if (t + 2 < NS) { a1_store(avs, ar, aseg, As[0]); b_store(bn, bk4, bvs, Bs[0]); }  // publish t+2
    __syncthreads();
  }

  // epilogue: SiLU -> f16 h rows. C/D: col=lane&15, row=(lane>>4)*4+q (verified).
  const int l15 = lane & 15, rq = (lane >> 4) * 4;
#pragma unroll
  for (int mf = 0; mf < 4; ++mf) {
#pragma unroll
    for (int q = 0; q < 4; ++q) {
      const int r = m0 + wr + mf * 16 + rq + q;
      if (r < n_e) {
        _Float16* hp = hbuf + (size_t)(off + r) * HDIM + n0 + wc + l15;
#pragma unroll
        for (int nf = 0; nf < 4; ++nf) {
          const float v = acc[mf][nf][q];
          hp[nf * 16] = (_Float16)(v / (1.f + __expf(-v)));
        }
      }
    }
  }
}

// ---------------- GEMM2: y[row] = h_e[row] @ W2[e] ----------------
__global__ __launch_bounds__(256) void gemm2_k(
    const _Float16* __restrict__ hbuf, const float* __restrict__ W2,
    const int* __restrict__ counts, _Float16* __restrict__ ybuf) {
  const int e = blockIdx.z;
  const int n_e = counts[e * 64];
  const int m0 = blockIdx.y * 128;
  if (m0 >= n_e) return;
  const int n0 = blockIdx.x * 128;
  int off = 0;
#pragma unroll
  for (int i = 0; i < NEXP; ++i) off += (i < e) ? counts[i * 64] : 0;

  __shared__ __align__(16) _Float16 As[2][128][40];
  __shared__ __align__(16) _Float16 Bs[2][128][40];

  const int tid = threadIdx.x, lane = tid & 63, w = tid >> 6;
  const int wr = (w >> 1) * 64, wc = (w & 1) * 64;

  const int ar = tid >> 1, aseg = (tid & 1) * 16;
  int rA = m0 + ar; if (rA >= n_e) rA = m0;          // clamp to a valid h row
  const int ao = (off + rA) * HDIM + aseg;           // int f16-elem offset (<2^27)
  const int bn = tid & 31, bk4 = (tid >> 5) * 4;
  const float* __restrict__ Wb = W2 + (size_t)e * HDIM * DDIM;   // uniform base
  const int bo = bk4 * DDIM + n0 + bn;

  f32x4 acc[4][4] = {};

  uint4 avs[2], avt[2]; float bvs[4][4], bvt[4][4];
  a2_loadi(hbuf, ao, avs);       b_loadi<DDIM>(Wb, bo, bvs);
  a2_loadi(hbuf, ao + 32, avt);  b_loadi<DDIM>(Wb, bo + 32 * DDIM, bvt);
  *(uint4*)&As[0][ar][aseg] = avs[0]; *(uint4*)&As[0][ar][aseg + 8] = avs[1];
  b_store(bn, bk4, bvs, Bs[0]);
  __syncthreads();

  constexpr int NS = HDIM / 32;                      // 128 K-steps
  for (int t = 0; t < NS; t += 2) {
    if (t + 2 < NS) { a2_loadi(hbuf, ao + (t + 2) * 32, avs); b_loadi<DDIM>(Wb, bo + (t + 2) * 32 * DDIM, bvs); }
    g_compute(As[0], Bs[0], wr, wc, lane, acc);      // step t
    *(uint4*)&As[1][ar][aseg] = avt[0]; *(uint4*)&As[1][ar][aseg + 8] = avt[1];
    b_store(bn, bk4, bvt, Bs[1]);                    // publish t+1
    __syncthreads();
    if (t + 3 < NS) { a2_loadi(hbuf, ao + (t + 3) * 32, avt); b_loadi<DDIM>(Wb, bo + (t + 3) * 32 * DDIM, bvt); }
    g_compute(As[1], Bs[1], wr, wc, lane, acc);      // step t+1
    if (t + 2 < NS) {
      *(uint4*)&As[0][ar][aseg] = avs[0]; *(uint4*)&As[0][ar][aseg + 8] = avs[1];
      b_store(bn, bk4, bvs, Bs[0]);                  // publish t+2
    }
    __syncthreads();
  }

  // epilogue: unweighted y rows, f16 (verified r7/r9/r10)
  const int l15 = lane & 15, rq = (lane >> 4) * 4;
#pragma unroll
  for (int mf = 0; mf < 4; ++mf) {
#pragma unroll
    for (int q = 0; q < 4; ++q) {
      const int r = m0 + wr + mf * 16 + rq + q;
      if (r < n_e) {
        _Float16* yp = ybuf + (size_t)(off + r) * DDIM + n0 + wc + l15;
#pragma unroll
        for (int nf = 0; nf < 4; ++nf) yp[nf * 16] = (_Float16)acc[mf][nf][q];
      }
    }
  }
}

// ---------------- Combine: out[t] = w0*y[slot0] + w1*y[slot1] (verified r7-r10) ----------------
__global__ __launch_bounds__(256) void combine_k(
    const _Float16* __restrict__ ybuf, const int* __restrict__ counts,
    const int* __restrict__ slots, const float* __restrict__ weights,
    float* __restrict__ out) {
  const int t = blockIdx.x;
  const int s0 = slots[t * 2], s1 = slots[t * 2 + 1];
  const int e0 = s0 >> 16, p0 = s0 & 0xFFFF;
  const int e1 = s1 >> 16, p1 = s1 & 0xFFFF;
  int off0 = 0, off1 = 0;
#pragma unroll
  for (int i = 0; i < NEXP; ++i) {
    const int c = counts[i * 64];
    off0 += (i < e0) ? c : 0;
    off1 += (i < e1) ? c : 0;
  }
  const float w0 = weights[e0 * TOK + p0];
  const float w1 = weights[e1 * TOK + p1];
  const int col = threadIdx.x * 4;
  const ushort4 u0 = *(const ushort4*)(ybuf + (size_t)(off0 + p0) * DDIM + col);
  const ushort4 u1 = *(const ushort4*)(ybuf + (size_t)(off1 + p1) * DDIM + col);
  float4 o;
  o.x = w0 * (float)__builtin_bit_cast(_Float16, u0.x) + w1 * (float)__builtin_bit_cast(_Float16, u1.x);
  o.y = w0 * (float)__builtin_bit_cast(_Float16, u0.y) + w1 * (float)__builtin_bit_cast(_Float16, u1.y);
  o.z = w0 * (float)__builtin_bit_cast(_Float16, u0.z) + w1 * (float)__builtin_bit_cast(_Float16, u1.z);
  o.w = w0 * (float)__builtin_bit_cast(_Float16, u0.w) + w1 * (float)__builtin_bit_cast(_Float16, u1.w);
  *(float4*)(out + (size_t)t * DDIM + col) = o;
}

// ---------------- Host launch ----------------
extern "C" void kernel_launch(void* const* d_in, const int* in_sizes, int n_in,
                              void* d_out, int out_size, void* d_ws, size_t ws_size,
                              hipStream_t stream) {
  const float* x  = (const float*)d_in[0];
  const float* Wr = (const float*)d_in[1];
  const float* W1 = (const float*)d_in[2];
  const float* W2 = (const float*)d_in[3];
  float* out = (float*)d_out;
  char* ws = (char*)d_ws;

  int*      counts  = (int*)(ws + OFF_COUNTS);
  int*      tokens  = (int*)(ws + OFF_TOKENS);
  float*    weights = (float*)(ws + OFF_WEIGHTS);
  int*      slots   = (int*)(ws + OFF_SLOTS);
  _Float16* hbuf    = (_Float16*)(ws + OFF_H);
  _Float16* ybuf    = (_Float16*)(ws + OFF_Y);

  hipMemsetAsync(counts, 0, 2048, stream);

  router_k<<<TOK / 4, 256, 0, stream>>>(x, Wr, counts, tokens, weights, slots);

  const dim3 g1(HDIM / 128, TOK / 128, NEXP);
  const dim3 g2(DDIM / 128, TOK / 128, NEXP);
  gemm1_k<<<g1, 256, 0, stream>>>(x, W1, counts, tokens, hbuf);
  gemm2_k<<<g2, 256, 0, stream>>>(hbuf, W2, counts, ybuf);
  combine_k<<<TOK, 256, 0, stream>>>(ybuf, counts, slots, weights, out);
}

// Round 13
// 992.939 us; speedup vs baseline: 1.2096x; 1.2096x over previous
//
#include <hip/hip_runtime.h>
#include <hip/hip_bf16.h>

// MoE MLP: B=4, L=2048, D=1024, E=8, H=4096, top-2. T=8192 tokens, 16384 assignments.
// Round 13 (= round 12 resubmit; bench never ran): base r10 (verified 868us) with
// BM 128->256, 512 threads, 8 waves (4Mx2N) -> per-thread B staging halves
// (gemm1 VALU was 2.4x MFMA). Int-offset saddr addressing kept (reg-light).
// r11's 2-deep prefetch stays reverted (it spilled: 670MB scratch WRITE_SIZE).

#define TOK  8192
#define DDIM 1024
#define NEXP 8
#define HDIM 4096

typedef __attribute__((ext_vector_type(8))) _Float16 f16x8;
typedef __attribute__((ext_vector_type(4))) float    f32x4;

static constexpr size_t OFF_COUNTS  = 0;
static constexpr size_t OFF_TOKENS  = 4096;
static constexpr size_t OFF_WEIGHTS = OFF_TOKENS + (size_t)NEXP * TOK * 4;
static constexpr size_t OFF_SLOTS   = OFF_WEIGHTS + (size_t)NEXP * TOK * 4;
static constexpr size_t OFF_H       = 1ull << 20;
static constexpr size_t OFF_Y       = OFF_H + (1ull << 27);

// ---------------- Router (verified r1/r5-r11) ----------------
__global__ __launch_bounds__(256) void router_k(
    const float* __restrict__ x, const float* __restrict__ Wr,
    int* __restrict__ counts, int* __restrict__ tokens, float* __restrict__ weights,
    int* __restrict__ slots) {
  const int lane = threadIdx.x & 63;
  const int t = blockIdx.x * 4 + (threadIdx.x >> 6);
  const float* xr = x + (size_t)t * DDIM;

  float acc[NEXP];
#pragma unroll
  for (int e = 0; e < NEXP; ++e) acc[e] = 0.f;

#pragma unroll
  for (int it = 0; it < DDIM / 256; ++it) {
    const int d = it * 256 + lane * 4;
    const float4 xv = *(const float4*)(xr + d);
    const float* wr = Wr + (size_t)d * NEXP;
#pragma unroll
    for (int j = 0; j < 4; ++j) {
      const float xs = (j == 0) ? xv.x : (j == 1) ? xv.y : (j == 2) ? xv.z : xv.w;
      const float4 w0 = *(const float4*)(wr + j * NEXP);
      const float4 w1 = *(const float4*)(wr + j * NEXP + 4);
      acc[0] = fmaf(xs, w0.x, acc[0]); acc[1] = fmaf(xs, w0.y, acc[1]);
      acc[2] = fmaf(xs, w0.z, acc[2]); acc[3] = fmaf(xs, w0.w, acc[3]);
      acc[4] = fmaf(xs, w1.x, acc[4]); acc[5] = fmaf(xs, w1.y, acc[5]);
      acc[6] = fmaf(xs, w1.z, acc[6]); acc[7] = fmaf(xs, w1.w, acc[7]);
    }
  }
#pragma unroll
  for (int e = 0; e < NEXP; ++e) {
#pragma unroll
    for (int off = 32; off > 0; off >>= 1) acc[e] += __shfl_xor(acc[e], off);
  }
  if (lane == 0) {
    int i0 = 0; float v0 = acc[0];
#pragma unroll
    for (int e = 1; e < NEXP; ++e) if (acc[e] > v0) { v0 = acc[e]; i0 = e; }
    int i1 = -1; float v1 = -3.4e38f;
#pragma unroll
    for (int e = 0; e < NEXP; ++e) if (e != i0 && acc[e] > v1) { v1 = acc[e]; i1 = e; }
    const float r = expf(v1 - v0);
    const float inv = 1.f / (1.f + r);
    const int p0 = atomicAdd(counts + i0 * 64, 1);
    tokens[i0 * TOK + p0] = t; weights[i0 * TOK + p0] = inv;
    const int p1 = atomicAdd(counts + i1 * 64, 1);
    tokens[i1 * TOK + p1] = t; weights[i1 * TOK + p1] = r * inv;
    slots[t * 2]     = (i0 << 16) | p0;
    slots[t * 2 + 1] = (i1 << 16) | p1;
  }
}

// LDS tiles [row][40] f16 (80B stride): b128 frag reads ~2-way (free);
// staged writes ~4-way. Verified r5/r6/r10.

// B staging (512 thr): thread covers k in {bk2, bk2+1}, n in {bn,+32,+64,+96}.
template <int LD>
__device__ __forceinline__ void b_loadi(const float* __restrict__ Wb, int o, float (&bv)[4][2]) {
#pragma unroll
  for (int g = 0; g < 4; ++g)
#pragma unroll
    for (int j = 0; j < 2; ++j)
      bv[g][j] = Wb[o + j * LD + 32 * g];
}

__device__ __forceinline__ void b_store(int bn, int bk2, const float (&bv)[4][2],
                                        _Float16 (*Bs)[40]) {
#pragma unroll
  for (int g = 0; g < 4; ++g) {
    const unsigned p = __builtin_bit_cast(unsigned, __builtin_amdgcn_cvt_pkrtz(bv[g][0], bv[g][1]));
    *(unsigned*)&Bs[bn + 32 * g][bk2] = p;
  }
}

__device__ __forceinline__ void a_loadi(const float* __restrict__ xb, int o, float4 (&av)[4]) {
#pragma unroll
  for (int j = 0; j < 4; ++j) av[j] = *(const float4*)(xb + o + j * 4);
}

__device__ __forceinline__ void a1_store(const float4 (&av)[4], int ar, int aseg,
                                         _Float16 (*As)[40]) {
  unsigned u[8];
#pragma unroll
  for (int j = 0; j < 4; ++j) {
    u[j * 2]     = __builtin_bit_cast(unsigned, __builtin_amdgcn_cvt_pkrtz(av[j].x, av[j].y));
    u[j * 2 + 1] = __builtin_bit_cast(unsigned, __builtin_amdgcn_cvt_pkrtz(av[j].z, av[j].w));
  }
  *(uint4*)&As[ar][aseg]     = make_uint4(u[0], u[1], u[2], u[3]);
  *(uint4*)&As[ar][aseg + 8] = make_uint4(u[4], u[5], u[6], u[7]);
}

// Fragment read + 16 MFMA (layouts HW-verified r5-r11).
__device__ __forceinline__ void g_compute(const _Float16 (*As)[40], const _Float16 (*Bs)[40],
                                          int wr, int wc, int lane, f32x4 (&acc)[4][4]) {
  const int l15 = lane & 15, g8 = (lane >> 4) * 8;
  f16x8 af[4], bf[4];
#pragma unroll
  for (int mf = 0; mf < 4; ++mf) af[mf] = *(const f16x8*)&As[wr + mf * 16 + l15][g8];
#pragma unroll
  for (int nf = 0; nf < 4; ++nf) bf[nf] = *(const f16x8*)&Bs[wc + nf * 16 + l15][g8];
#pragma unroll
  for (int mf = 0; mf < 4; ++mf)
#pragma unroll
    for (int nf = 0; nf < 4; ++nf)
      acc[mf][nf] = __builtin_amdgcn_mfma_f32_16x16x32_f16(af[mf], bf[nf], acc[mf][nf], 0, 0, 0);
}

// ---------------- GEMM1: h = silu(gather(x) @ W1[e]), 256x128 tile ----------------
__global__ __launch_bounds__(512) void gemm1_k(
    const float* __restrict__ x, const float* __restrict__ W1,
    const int* __restrict__ counts, const int* __restrict__ tokens,
    _Float16* __restrict__ hbuf) {
  const int e = blockIdx.z;
  const int n_e = counts[e * 64];
  const int m0 = blockIdx.y * 256;
  if (m0 >= n_e) return;
  const int n0 = blockIdx.x * 128;
  int off = 0;
#pragma unroll
  for (int i = 0; i < NEXP; ++i) off += (i < e) ? counts[i * 64] : 0;

  __shared__ __align__(16) _Float16 As[2][256][40];   // 20KB x2
  __shared__ __align__(16) _Float16 Bs[2][128][40];   // 10KB x2 -> 60KB total

  const int tid = threadIdx.x, lane = tid & 63, w = tid >> 6;       // 8 waves
  const int wr = (w >> 1) * 64, wc = (w & 1) * 64;                   // 4M x 2N

  const int ar = tid >> 1, aseg = (tid & 1) * 16;                    // 256 rows
  const int rA = m0 + ar;
  const int tokA = (rA < n_e) ? tokens[e * TOK + rA] : 0;
  const int ao = tokA * DDIM + aseg;
  const int bn = tid & 31, bk2 = (tid >> 5) * 2;                     // 16 k-groups
  const float* __restrict__ Wb = W1 + (size_t)e * DDIM * HDIM;
  const int bo = bk2 * HDIM + n0 + bn;

  f32x4 acc[4][4] = {};

  float4 av[4]; float bv[4][2];
  a_loadi(x, ao, av);
  b_loadi<HDIM>(Wb, bo, bv);
  a1_store(av, ar, aseg, As[0]);
  b_store(bn, bk2, bv, Bs[0]);
  __syncthreads();

  int cur = 0;
  constexpr int NS = DDIM / 32;
  for (int t = 0; t < NS - 1; ++t) {
    a_loadi(x, ao + (t + 1) * 32, av);
    b_loadi<HDIM>(Wb, bo + (t + 1) * 32 * HDIM, bv);
    g_compute(As[cur], Bs[cur], wr, wc, lane, acc);
    a1_store(av, ar, aseg, As[cur ^ 1]);
    b_store(bn, bk2, bv, Bs[cur ^ 1]);
    __syncthreads();
    cur ^= 1;
  }
  g_compute(As[cur], Bs[cur], wr, wc, lane, acc);

  // epilogue: SiLU -> f16 h rows. C/D: col=lane&15, row=(lane>>4)*4+q (verified).
  const int l15 = lane & 15, rq = (lane >> 4) * 4;
#pragma unroll
  for (int mf = 0; mf < 4; ++mf) {
#pragma unroll
    for (int q = 0; q < 4; ++q) {
      const int r = m0 + wr + mf * 16 + rq + q;
      if (r < n_e) {
        _Float16* hp = hbuf + (size_t)(off + r) * HDIM + n0 + wc + l15;
#pragma unroll
        for (int nf = 0; nf < 4; ++nf) {
          const float v = acc[mf][nf][q];
          hp[nf * 16] = (_Float16)(v / (1.f + __expf(-v)));
        }
      }
    }
  }
}

// ---------------- GEMM2: y[row] = h_e[row] @ W2[e], 256x128 tile ----------------
__global__ __launch_bounds__(512) void gemm2_k(
    const _Float16* __restrict__ hbuf, const float* __restrict__ W2,
    const int* __restrict__ counts, _Float16* __restrict__ ybuf) {
  const int e = blockIdx.z;
  const int n_e = counts[e * 64];
  const int m0 = blockIdx.y * 256;
  if (m0 >= n_e) return;
  const int n0 = blockIdx.x * 128;
  int off = 0;
#pragma unroll
  for (int i = 0; i < NEXP; ++i) off += (i < e) ? counts[i * 64] : 0;

  __shared__ __align__(16) _Float16 As[2][256][40];
  __shared__ __align__(16) _Float16 Bs[2][128][40];

  const int tid = threadIdx.x, lane = tid & 63, w = tid >> 6;
  const int wr = (w >> 1) * 64, wc = (w & 1) * 64;

  const int ar = tid >> 1, aseg = (tid & 1) * 16;
  int rA = m0 + ar; if (rA >= n_e) rA = m0;          // clamp to a valid h row
  const int ao = (off + rA) * HDIM + aseg;           // f16-elem offset (<2^27)
  const int bn = tid & 31, bk2 = (tid >> 5) * 2;
  const float* __restrict__ Wb = W2 + (size_t)e * HDIM * DDIM;
  const int bo = bk2 * DDIM + n0 + bn;

  f32x4 acc[4][4] = {};

  uint4 av[2]; float bv[4][2];
  av[0] = *(const uint4*)(hbuf + ao);
  av[1] = *(const uint4*)(hbuf + ao + 8);
  b_loadi<DDIM>(Wb, bo, bv);
  *(uint4*)&As[0][ar][aseg] = av[0]; *(uint4*)&As[0][ar][aseg + 8] = av[1];
  b_store(bn, bk2, bv, Bs[0]);
  __syncthreads();

  int cur = 0;
  constexpr int NS = HDIM / 32;
  for (int t = 0; t < NS - 1; ++t) {
    const int kn = (t + 1) * 32;
    av[0] = *(const uint4*)(hbuf + ao + kn);
    av[1] = *(const uint4*)(hbuf + ao + kn + 8);
    b_loadi<DDIM>(Wb, bo + kn * DDIM, bv);
    g_compute(As[cur], Bs[cur], wr, wc, lane, acc);
    *(uint4*)&As[cur ^ 1][ar][aseg] = av[0]; *(uint4*)&As[cur ^ 1][ar][aseg + 8] = av[1];
    b_store(bn, bk2, bv, Bs[cur ^ 1]);
    __syncthreads();
    cur ^= 1;
  }
  g_compute(As[cur], Bs[cur], wr, wc, lane, acc);

  // epilogue: unweighted y rows, f16 (verified r7-r11)
  const int l15 = lane & 15, rq = (lane >> 4) * 4;
#pragma unroll
  for (int mf = 0; mf < 4; ++mf) {
#pragma unroll
    for (int q = 0; q < 4; ++q) {
      const int r = m0 + wr + mf * 16 + rq + q;
      if (r < n_e) {
        _Float16* yp = ybuf + (size_t)(off + r) * DDIM + n0 + wc + l15;
#pragma unroll
        for (int nf = 0; nf < 4; ++nf) yp[nf * 16] = (_Float16)acc[mf][nf][q];
      }
    }
  }
}

// ---------------- Combine: out[t] = w0*y[slot0] + w1*y[slot1] (verified r7-r11) ----------------
__global__ __launch_bounds__(256) void combine_k(
    const _Float16* __restrict__ ybuf, const int* __restrict__ counts,
    const int* __restrict__ slots, const float* __restrict__ weights,
    float* __restrict__ out) {
  const int t = blockIdx.x;
  const int s0 = slots[t * 2], s1 = slots[t * 2 + 1];
  const int e0 = s0 >> 16, p0 = s0 & 0xFFFF;
  const int e1 = s1 >> 16, p1 = s1 & 0xFFFF;
  int off0 = 0, off1 = 0;
#pragma unroll
  for (int i = 0; i < NEXP; ++i) {
    const int c = counts[i * 64];
    off0 += (i < e0) ? c : 0;
    off1 += (i < e1) ? c : 0;
  }
  const float w0 = weights[e0 * TOK + p0];
  const float w1 = weights[e1 * TOK + p1];
  const int col = threadIdx.x * 4;
  const ushort4 u0 = *(const ushort4*)(ybuf + (size_t)(off0 + p0) * DDIM + col);
  const ushort4 u1 = *(const ushort4*)(ybuf + (size_t)(off1 + p1) * DDIM + col);
  float4 o;
  o.x = w0 * (float)__builtin_bit_cast(_Float16, u0.x) + w1 * (float)__builtin_bit_cast(_Float16, u1.x);
  o.y = w0 * (float)__builtin_bit_cast(_Float16, u0.y) + w1 * (float)__builtin_bit_cast(_Float16, u1.y);
  o.z = w0 * (float)__builtin_bit_cast(_Float16, u0.z) + w1 * (float)__builtin_bit_cast(_Float16, u1.z);
  o.w = w0 * (float)__builtin_bit_cast(_Float16, u0.w) + w1 * (float)__builtin_bit_cast(_Float16, u1.w);
  *(float4*)(out + (size_t)t * DDIM + col) = o;
}

// ---------------- Host launch ----------------
extern "C" void kernel_launch(void* const* d_in, const int* in_sizes, int n_in,
                              void* d_out, int out_size, void* d_ws, size_t ws_size,
                              hipStream_t stream) {
  const float* x  = (const float*)d_in[0];
  const float* Wr = (const float*)d_in[1];
  const float* W1 = (const float*)d_in[2];
  const float* W2 = (const float*)d_in[3];
  float* out = (float*)d_out;
  char* ws = (char*)d_ws;

  int*      counts  = (int*)(ws + OFF_COUNTS);
  int*      tokens  = (int*)(ws + OFF_TOKENS);
  float*    weights = (float*)(ws + OFF_WEIGHTS);
  int*      slots   = (int*)(ws + OFF_SLOTS);
  _Float16* hbuf    = (_Float16*)(ws + OFF_H);
  _Float16* ybuf    = (_Float16*)(ws + OFF_Y);

  hipMemsetAsync(counts, 0, 2048, stream);

  router_k<<<TOK / 4, 256, 0, stream>>>(x, Wr, counts, tokens, weights, slots);

  const dim3 g1(HDIM / 128, TOK / 256, NEXP);
  const dim3 g2(DDIM / 128, TOK / 256, NEXP);
  gemm1_k<<<g1, 512, 0, stream>>>(x, W1, counts, tokens, hbuf);
  gemm2_k<<<g2, 512, 0, stream>>>(hbuf, W2, counts, ybuf);
  combine_k<<<TOK, 256, 0, stream>>>(ybuf, counts, slots, weights, out);
}